// Round 10
// baseline (164.233 us; speedup 1.0000x reference)
//
#include <hip/hip_runtime.h>

#define IMG 512

typedef short short8  __attribute__((ext_vector_type(8)));
typedef float floatx4 __attribute__((ext_vector_type(4)));
typedef unsigned uvec2 __attribute__((ext_vector_type(2)));

// 1D Gaussian (sigma=1.5, K=11) — identical values to prior rounds.
__device__ static constexpr float W11F[11] = {
    0.00102838f, 0.00759876f, 0.03600077f, 0.10936069f, 0.21300554f,
    0.26601173f,
    0.21300554f, 0.10936069f, 0.03600077f, 0.00759876f, 0.00102838f};

// pack two fp32 -> one u32 of two bf16 (round-half-up; verified rounds 0-9)
__device__ __forceinline__ unsigned pack2bf16(float a, float b) {
    const unsigned ua = __float_as_uint(a) + 0x8000u;
    const unsigned ub = __float_as_uint(b) + 0x8000u;
    return __builtin_amdgcn_perm(ub, ua, 0x07060302u);
}

// RESIDENCY-SCALED LDS-free kernel. Empirical law from rounds 0-9: every
// wave pays ~10.2k cycles per 16x16 output window (~91% stall), chains of
// co-resident waves run in parallel, wall = windows/wave x 10.2k x
// generations. Round 9 (16 win/wave, 3 waves/SIMD, 1 gen) = 68us; round 0
// (4 win/wave but ~2.7 blocks/CU resident -> 4.4 gens) = 75us. This round:
// round-9 kernel (VGPR 64, zero loop LDS -> nothing caps residency)
// reshaped to 128-row strips: grid 8x4x48 = 1536 blocks = 6 blocks/CU =
// 24 waves/CU in ONE generation, 8 windows/wave (9 tiles). Predicted wall
// ~8 x 10.2k ~ 34us. Everything else identical to round 9: H-pass and
// V-pass MFMAs linked by pure-VALU permlane16/32_swap redistribution
// (no LDS round trip), 2 register buffer sets, no barriers in loop.
__global__ __launch_bounds__(256) void ssim_mfma_reg(
        const float* __restrict__ pred, const float* __restrict__ gt,
        float* __restrict__ partials)
{
    __shared__ ushort wlut[16];
    __shared__ float wsum[4];

    const int tid  = threadIdx.x;
    const int wv   = tid >> 6;
    const int lane = tid & 63;
    const int n    = lane & 15;
    const int quad = lane >> 4;

    if (tid < 16) {
        const float w = (tid < 11) ? W11F[tid] : 0.f;
        wlut[tid] = (ushort)((__float_as_uint(w) + 0x8000u) >> 16);
    }
    __syncthreads();

    // band fragment: w[(quad*8+j) - n - 3]; B in H-pass, A in V-pass.
    short8 band;
#pragma unroll
    for (int j = 0; j < 8; ++j) {
        const int t = quad * 8 + j - n - 3;
        band[j] = (short)wlut[((unsigned)t < 11u) ? t : 15];
    }

    const int bx = blockIdx.x, yh = blockIdx.y, plane = blockIdx.z;
    const long pb = (long)plane * (IMG * IMG);
    const float* pplane = pred + pb;
    const float* gplane = gt + pb;
    const int xs  = bx * 64 + wv * 16 - 8;  // 32-col input window start
    const int y0  = yh * 128;               // 128-row output strip
    const bool cols_ok = (xs >= 0) && (xs + 32 <= IMG);

// stage tile t (16 input rows starting at y0-8+16t) into named buffers
#define LOADT(t, pf, gf)                                                     \
    {                                                                        \
        const int ys  = y0 - 8 + (t) * 16;                                   \
        const int row = ys + n;                                              \
        const int c0  = xs + quad * 8;                                       \
        if (cols_ok && ys >= 0 && ys + 16 <= IMG) {                          \
            const float* pr = pplane + (long)row * IMG + c0;                 \
            const float* gr = gplane + (long)row * IMG + c0;                 \
            *(float4*)&pf[0] = *(const float4*)pr;                           \
            *(float4*)&pf[4] = *(const float4*)(pr + 4);                     \
            *(float4*)&gf[0] = *(const float4*)gr;                           \
            *(float4*)&gf[4] = *(const float4*)(gr + 4);                     \
        } else {                                                             \
            const bool rv = (unsigned)row < (unsigned)IMG;                   \
            const int rowc = rv ? row : 0;                                   \
            const float* pr = pplane + (long)rowc * IMG;                     \
            const float* gr = gplane + (long)rowc * IMG;                     \
            _Pragma("unroll")                                                \
            for (int j = 0; j < 8; ++j) {                                    \
                const int cc = c0 + j;                                       \
                const bool ok = rv && ((unsigned)cc < (unsigned)IMG);        \
                const int ccc = ok ? cc : 0;                                 \
                const float pv = pr[ccc], gv = gr[ccc];                      \
                pf[j] = ok ? pv : 0.f;                                       \
                gf[j] = ok ? gv : 0.f;                                       \
            }                                                                \
        }                                                                    \
    }

// H-conv tile via 5 MFMAs; pack D into PK[10] (2 u32 per quantity):
// PK[2q+i] covers rows (4*quad + 2i, +1) of quantity q at out-col n.
#define COMPH(pf, gf, PK)                                                    \
    {                                                                        \
        union { unsigned u[4]; short8 s; } ap, ag, app, agg, apg;            \
        _Pragma("unroll")                                                    \
        for (int h = 0; h < 4; ++h) {                                        \
            const float p0 = pf[2*h], p1 = pf[2*h+1];                        \
            const float g0 = gf[2*h], g1 = gf[2*h+1];                        \
            ap.u [h] = pack2bf16(p0, p1);                                    \
            ag.u [h] = pack2bf16(g0, g1);                                    \
            app.u[h] = pack2bf16(p0 * p0, p1 * p1);                          \
            agg.u[h] = pack2bf16(g0 * g0, g1 * g1);                          \
            apg.u[h] = pack2bf16(p0 * g0, p1 * g1);                          \
        }                                                                    \
        const floatx4 z = {0.f, 0.f, 0.f, 0.f};                              \
        const floatx4 cp  = __builtin_amdgcn_mfma_f32_16x16x32_bf16(ap.s,  band, z, 0, 0, 0); \
        const floatx4 cg  = __builtin_amdgcn_mfma_f32_16x16x32_bf16(ag.s,  band, z, 0, 0, 0); \
        const floatx4 cpp = __builtin_amdgcn_mfma_f32_16x16x32_bf16(app.s, band, z, 0, 0, 0); \
        const floatx4 cgg = __builtin_amdgcn_mfma_f32_16x16x32_bf16(agg.s, band, z, 0, 0, 0); \
        const floatx4 cpg = __builtin_amdgcn_mfma_f32_16x16x32_bf16(apg.s, band, z, 0, 0, 0); \
        PK[0] = pack2bf16(cp [0], cp [1]); PK[1] = pack2bf16(cp [2], cp [3]); \
        PK[2] = pack2bf16(cg [0], cg [1]); PK[3] = pack2bf16(cg [2], cg [3]); \
        PK[4] = pack2bf16(cpp[0], cpp[1]); PK[5] = pack2bf16(cpp[2], cpp[3]); \
        PK[6] = pack2bf16(cgg[0], cgg[1]); PK[7] = pack2bf16(cgg[2], cgg[3]); \
        PK[8] = pack2bf16(cpg[0], cpg[1]); PK[9] = pack2bf16(cpg[2], cpg[3]); \
    }

// build V-pass B-fragment for quantity q from packed LO/HI tiles:
// dest quad q' element j = H-row (8q' + j) of tile (q'<2 ? LO : HI)
#define BFRAG(PLO, PHI, q, OUT)                                              \
    short8 OUT;                                                              \
    {                                                                        \
        const uvec2 s0 = __builtin_amdgcn_permlane32_swap(                   \
            PLO[2*(q)],     PHI[2*(q)],     false, false);                   \
        const uvec2 t0 = __builtin_amdgcn_permlane16_swap(                   \
            s0[0], s0[1], false, false);                                     \
        const uvec2 s1 = __builtin_amdgcn_permlane32_swap(                   \
            PLO[2*(q)+1],   PHI[2*(q)+1],   false, false);                   \
        const uvec2 t1 = __builtin_amdgcn_permlane16_swap(                   \
            s1[0], s1[1], false, false);                                     \
        union { unsigned u[4]; short8 s; } b_;                               \
        b_.u[0] = t0[0]; b_.u[1] = t1[0]; b_.u[2] = t0[1]; b_.u[3] = t1[1];  \
        OUT = b_.s;                                                          \
    }

// V window: LO = packed tile w, HI = packed tile w+1 (in-register)
#define VWIN(PLO, PHI)                                                       \
    {                                                                        \
        BFRAG(PLO, PHI, 0, bp)                                               \
        BFRAG(PLO, PHI, 1, bg)                                               \
        BFRAG(PLO, PHI, 2, bpp)                                              \
        BFRAG(PLO, PHI, 3, bgg)                                              \
        BFRAG(PLO, PHI, 4, bpg)                                              \
        const floatx4 z = {0.f, 0.f, 0.f, 0.f};                              \
        const floatx4 mp  = __builtin_amdgcn_mfma_f32_16x16x32_bf16(band, bp,  z, 0, 0, 0); \
        const floatx4 mg  = __builtin_amdgcn_mfma_f32_16x16x32_bf16(band, bg,  z, 0, 0, 0); \
        const floatx4 mpp = __builtin_amdgcn_mfma_f32_16x16x32_bf16(band, bpp, z, 0, 0, 0); \
        const floatx4 mgg = __builtin_amdgcn_mfma_f32_16x16x32_bf16(band, bgg, z, 0, 0, 0); \
        const floatx4 mpg = __builtin_amdgcn_mfma_f32_16x16x32_bf16(band, bpg, z, 0, 0, 0); \
        _Pragma("unroll")                                                    \
        for (int r = 0; r < 4; ++r) {                                        \
            const float mu1 = mp[r], mu2 = mg[r];                            \
            const float mu1sq = mu1 * mu1, mu2sq = mu2 * mu2;                \
            const float mu12 = mu1 * mu2;                                    \
            const float s1  = mpp[r] - mu1sq;                                \
            const float s2  = mgg[r] - mu2sq;                                \
            const float s12 = mpg[r] - mu12;                                 \
            const float num = (2.f * mu12 + C1) * (2.f * s12 + C2);          \
            const float den = (mu1sq + mu2sq + C1) * (s1 + s2 + C2);         \
            lsum += num * __builtin_amdgcn_rcpf(den);                        \
        }                                                                    \
    }

    const float C1 = 1e-4f, C2 = 9e-4f;
    float lsum = 0.f;

    // named register state only: 2 load buffer sets + 2 packed-tile sets
    float pA[8], gA[8], pB[8], gB[8];
    unsigned PKE[10], PKO[10];

    // ---- pipeline fill ----
    LOADT(0, pA, gA)
    LOADT(1, pB, gB)
    COMPH(pA, gA, PKE)        // tile 0
    LOADT(2, pA, gA)
    COMPH(pB, gB, PKO)        // tile 1
    VWIN(PKE, PKO)            // window 0: tiles 0,1

    // ---- steady state: 2 tiles / 2 windows per iteration ----
    for (int t = 2; t <= 6; t += 2) {
        LOADT(t + 1, pB, gB)
        COMPH(pA, gA, PKE)    // tile t
        VWIN(PKO, PKE)        // window t-1: tiles t-1,t
        LOADT(t + 2, pA, gA)
        COMPH(pB, gB, PKO)    // tile t+1
        VWIN(PKE, PKO)        // window t: tiles t,t+1
    }

    // ---- drain: tiles 0..8 loaded, windows 0..6 done ----
    COMPH(pA, gA, PKE)        // tile 8
    VWIN(PKO, PKE)            // window 7: tiles 7,8

    // ---- block reduction -> one partial per block ----
#pragma unroll
    for (int off = 32; off > 0; off >>= 1)
        lsum += __shfl_down(lsum, off);
    if (lane == 0) wsum[wv] = lsum;
    __syncthreads();
    if (tid == 0)
        partials[(plane * 4 + yh) * 8 + bx] =
            wsum[0] + wsum[1] + wsum[2] + wsum[3];
}

__global__ __launch_bounds__(1024) void ssim_finalize(
        const float* __restrict__ partials, float* __restrict__ out,
        int nparts, double inv_n)
{
    __shared__ double ws[16];
    double s = 0.0;
    for (int i = threadIdx.x; i < nparts; i += 1024)
        s += (double)partials[i];
#pragma unroll
    for (int off = 32; off > 0; off >>= 1)
        s += __shfl_down(s, off);
    if ((threadIdx.x & 63) == 0) ws[threadIdx.x >> 6] = s;
    __syncthreads();
    if (threadIdx.x == 0) {
        double t = 0.0;
#pragma unroll
        for (int i = 0; i < 16; ++i) t += ws[i];
        out[0] = (float)(1.0 - t * inv_n);
    }
}

extern "C" void kernel_launch(void* const* d_in, const int* in_sizes, int n_in,
                              void* d_out, int out_size, void* d_ws, size_t ws_size,
                              hipStream_t stream)
{
    const float* pred = (const float*)d_in[0];
    const float* gt   = (const float*)d_in[1];
    float* out        = (float*)d_out;
    float* partials   = (float*)d_ws;          // 8*4*48 = 1536 floats

    const long n = (long)in_sizes[0];
    const int planes = (int)(n / (long)(IMG * IMG));   // B*C = 48

    dim3 grid(8, 4, planes);                   // 64-col x 128-row strips
    ssim_mfma_reg<<<grid, 256, 0, stream>>>(pred, gt, partials);
    ssim_finalize<<<1, 1024, 0, stream>>>(partials, out,
                                          8 * 4 * planes, 1.0 / (double)n);
}

// Round 11
// 137.016 us; speedup vs baseline: 1.1986x; 1.1986x over previous
//
#include <hip/hip_runtime.h>

#define IMG 512

typedef short short8  __attribute__((ext_vector_type(8)));
typedef float floatx4 __attribute__((ext_vector_type(4)));
typedef unsigned uvec2 __attribute__((ext_vector_type(2)));

// 1D Gaussian (sigma=1.5, K=11) — identical values to prior rounds.
__device__ static constexpr float W11F[11] = {
    0.00102838f, 0.00759876f, 0.03600077f, 0.10936069f, 0.21300554f,
    0.26601173f,
    0.21300554f, 0.10936069f, 0.03600077f, 0.00759876f, 0.00102838f};

// pack two fp32 -> one u32 of two bf16 (round-half-up; verified rounds 0-10)
__device__ __forceinline__ unsigned pack2bf16(float a, float b) {
    const unsigned ua = __float_as_uint(a) + 0x8000u;
    const unsigned ub = __float_as_uint(b) + 0x8000u;
    return __builtin_amdgcn_perm(ub, ua, 0x07060302u);
}

// CODE-SIZE-TRIMMED LDS-free kernel (I$-fit). Rounds 0-10 model: every
// variant was instruction-fetch bound — fully-unrolled 40-60KB bodies
// overflow the 32KB I$; each wave streams ~2.6KB of unique code per
// window from L2 (~40 lines x ~250cy = the measured ~10.2k cyc/window),
// waves at different PCs thrash rather than share, so duration was
// invariant to occupancy/data-source/staging and VALUBusy pinned ~26%.
// Fix: (1) steady loop ROLLED (#pragma unroll 1, runtime t) -> ~6KB hot
// body shared by all waves; (2) LOADT's 70-inst scalar edge path replaced
// by branch-free clamped loads + cndmask zeroing (legal: c0 = 0 mod 8 so
// each lane's 8-col group is all-in-bounds or all-out; rows clamp).
// Everything else identical to round 9 (68us best): H/V MFMA passes
// linked by permlane16/32_swap, 2 register buffer sets, no loop LDS.
__global__ __launch_bounds__(256) void ssim_mfma_small(
        const float* __restrict__ pred, const float* __restrict__ gt,
        float* __restrict__ partials)
{
    __shared__ ushort wlut[16];
    __shared__ float wsum[4];

    const int tid  = threadIdx.x;
    const int wv   = tid >> 6;
    const int lane = tid & 63;
    const int n    = lane & 15;
    const int quad = lane >> 4;

    if (tid < 16) {
        const float w = (tid < 11) ? W11F[tid] : 0.f;
        wlut[tid] = (ushort)((__float_as_uint(w) + 0x8000u) >> 16);
    }
    __syncthreads();

    // band fragment: w[(quad*8+j) - n - 3]; B in H-pass, A in V-pass.
    short8 band;
#pragma unroll
    for (int j = 0; j < 8; ++j) {
        const int t = quad * 8 + j - n - 3;
        band[j] = (short)wlut[((unsigned)t < 11u) ? t : 15];
    }

    const int bx = blockIdx.x, yh = blockIdx.y, plane = blockIdx.z;
    const long pb = (long)plane * (IMG * IMG);
    const float* pplane = pred + pb;
    const float* gplane = gt + pb;
    const int xs  = bx * 64 + wv * 16 - 8;  // 32-col input window start
    const int y0  = yh * 256;               // 256-row output strip

    // per-lane column group: c0 = 0 mod 8, range [-8, 512] -> the lane's
    // 8 columns are either ALL in-bounds or ALL out-of-bounds.
    const int  c0     = xs + quad * 8;
    const bool cvalid = (c0 >= 0) && (c0 + 8 <= IMG);
    const int  c0c    = cvalid ? c0 : 0;

// stage tile t (16 input rows starting at y0-8+16t): branch-free.
// Clamped row/col addresses; OOB lanes zeroed via selects (ref zero-pad).
#define LOADT(t, pf, gf)                                                     \
    {                                                                        \
        const int row  = y0 - 8 + (t) * 16 + n;                              \
        const int rowc = row < 0 ? 0 : (row > IMG - 1 ? IMG - 1 : row);      \
        const bool lok = cvalid && ((unsigned)row < (unsigned)IMG);          \
        const float* pr = pplane + (long)rowc * IMG + c0c;                   \
        const float* gr = gplane + (long)rowc * IMG + c0c;                   \
        const float4 p0 = *(const float4*)pr;                                \
        const float4 p1 = *(const float4*)(pr + 4);                          \
        const float4 g0 = *(const float4*)gr;                                \
        const float4 g1 = *(const float4*)(gr + 4);                          \
        _Pragma("unroll")                                                    \
        for (int j = 0; j < 4; ++j) {                                        \
            pf[j]     = lok ? p0[j] : 0.f;                                   \
            pf[j + 4] = lok ? p1[j] : 0.f;                                   \
            gf[j]     = lok ? g0[j] : 0.f;                                   \
            gf[j + 4] = lok ? g1[j] : 0.f;                                   \
        }                                                                    \
    }

// H-conv tile via 5 MFMAs; pack D into PK[10] (2 u32 per quantity):
// PK[2q+i] covers rows (4*quad + 2i, +1) of quantity q at out-col n.
#define COMPH(pf, gf, PK)                                                    \
    {                                                                        \
        union { unsigned u[4]; short8 s; } ap, ag, app, agg, apg;            \
        _Pragma("unroll")                                                    \
        for (int h = 0; h < 4; ++h) {                                        \
            const float p0 = pf[2*h], p1 = pf[2*h+1];                        \
            const float g0 = gf[2*h], g1 = gf[2*h+1];                        \
            ap.u [h] = pack2bf16(p0, p1);                                    \
            ag.u [h] = pack2bf16(g0, g1);                                    \
            app.u[h] = pack2bf16(p0 * p0, p1 * p1);                          \
            agg.u[h] = pack2bf16(g0 * g0, g1 * g1);                          \
            apg.u[h] = pack2bf16(p0 * g0, p1 * g1);                          \
        }                                                                    \
        const floatx4 z = {0.f, 0.f, 0.f, 0.f};                              \
        const floatx4 cp  = __builtin_amdgcn_mfma_f32_16x16x32_bf16(ap.s,  band, z, 0, 0, 0); \
        const floatx4 cg  = __builtin_amdgcn_mfma_f32_16x16x32_bf16(ag.s,  band, z, 0, 0, 0); \
        const floatx4 cpp = __builtin_amdgcn_mfma_f32_16x16x32_bf16(app.s, band, z, 0, 0, 0); \
        const floatx4 cgg = __builtin_amdgcn_mfma_f32_16x16x32_bf16(agg.s, band, z, 0, 0, 0); \
        const floatx4 cpg = __builtin_amdgcn_mfma_f32_16x16x32_bf16(apg.s, band, z, 0, 0, 0); \
        PK[0] = pack2bf16(cp [0], cp [1]); PK[1] = pack2bf16(cp [2], cp [3]); \
        PK[2] = pack2bf16(cg [0], cg [1]); PK[3] = pack2bf16(cg [2], cg [3]); \
        PK[4] = pack2bf16(cpp[0], cpp[1]); PK[5] = pack2bf16(cpp[2], cpp[3]); \
        PK[6] = pack2bf16(cgg[0], cgg[1]); PK[7] = pack2bf16(cgg[2], cgg[3]); \
        PK[8] = pack2bf16(cpg[0], cpg[1]); PK[9] = pack2bf16(cpg[2], cpg[3]); \
    }

// build V-pass B-fragment for quantity q from packed LO/HI tiles:
// dest quad q' element j = H-row (8q' + j) of tile (q'<2 ? LO : HI)
#define BFRAG(PLO, PHI, q, OUT)                                              \
    short8 OUT;                                                              \
    {                                                                        \
        const uvec2 s0 = __builtin_amdgcn_permlane32_swap(                   \
            PLO[2*(q)],     PHI[2*(q)],     false, false);                   \
        const uvec2 t0 = __builtin_amdgcn_permlane16_swap(                   \
            s0[0], s0[1], false, false);                                     \
        const uvec2 s1 = __builtin_amdgcn_permlane32_swap(                   \
            PLO[2*(q)+1],   PHI[2*(q)+1],   false, false);                   \
        const uvec2 t1 = __builtin_amdgcn_permlane16_swap(                   \
            s1[0], s1[1], false, false);                                     \
        union { unsigned u[4]; short8 s; } b_;                               \
        b_.u[0] = t0[0]; b_.u[1] = t1[0]; b_.u[2] = t0[1]; b_.u[3] = t1[1];  \
        OUT = b_.s;                                                          \
    }

// V window: LO = packed tile w, HI = packed tile w+1 (in-register)
#define VWIN(PLO, PHI)                                                       \
    {                                                                        \
        BFRAG(PLO, PHI, 0, bp)                                               \
        BFRAG(PLO, PHI, 1, bg)                                               \
        BFRAG(PLO, PHI, 2, bpp)                                              \
        BFRAG(PLO, PHI, 3, bgg)                                              \
        BFRAG(PLO, PHI, 4, bpg)                                              \
        const floatx4 z = {0.f, 0.f, 0.f, 0.f};                              \
        const floatx4 mp  = __builtin_amdgcn_mfma_f32_16x16x32_bf16(band, bp,  z, 0, 0, 0); \
        const floatx4 mg  = __builtin_amdgcn_mfma_f32_16x16x32_bf16(band, bg,  z, 0, 0, 0); \
        const floatx4 mpp = __builtin_amdgcn_mfma_f32_16x16x32_bf16(band, bpp, z, 0, 0, 0); \
        const floatx4 mgg = __builtin_amdgcn_mfma_f32_16x16x32_bf16(band, bgg, z, 0, 0, 0); \
        const floatx4 mpg = __builtin_amdgcn_mfma_f32_16x16x32_bf16(band, bpg, z, 0, 0, 0); \
        _Pragma("unroll")                                                    \
        for (int r = 0; r < 4; ++r) {                                        \
            const float mu1 = mp[r], mu2 = mg[r];                            \
            const float mu1sq = mu1 * mu1, mu2sq = mu2 * mu2;                \
            const float mu12 = mu1 * mu2;                                    \
            const float s1  = mpp[r] - mu1sq;                                \
            const float s2  = mgg[r] - mu2sq;                                \
            const float s12 = mpg[r] - mu12;                                 \
            const float num = (2.f * mu12 + C1) * (2.f * s12 + C2);          \
            const float den = (mu1sq + mu2sq + C1) * (s1 + s2 + C2);         \
            lsum += num * __builtin_amdgcn_rcpf(den);                        \
        }                                                                    \
    }

    const float C1 = 1e-4f, C2 = 9e-4f;
    float lsum = 0.f;

    // named register state only: 2 load buffer sets + 2 packed-tile sets
    float pA[8], gA[8], pB[8], gB[8];
    unsigned PKE[10], PKO[10];

    // ---- pipeline fill ----
    LOADT(0, pA, gA)
    LOADT(1, pB, gB)
    COMPH(pA, gA, PKE)        // tile 0
    LOADT(2, pA, gA)
    COMPH(pB, gB, PKO)        // tile 1
    VWIN(PKE, PKO)            // window 0: tiles 0,1

    // ---- steady state: ROLLED loop (I$-resident hot body) ----
#pragma unroll 1
    for (int t = 2; t <= 14; t += 2) {
        LOADT(t + 1, pB, gB)
        COMPH(pA, gA, PKE)    // tile t
        VWIN(PKO, PKE)        // window t-1: tiles t-1,t
        LOADT(t + 2, pA, gA)
        COMPH(pB, gB, PKO)    // tile t+1
        VWIN(PKE, PKO)        // window t: tiles t,t+1
    }

    // ---- drain: tiles 0..16 loaded, windows 0..14 done ----
    COMPH(pA, gA, PKE)        // tile 16
    VWIN(PKO, PKE)            // window 15: tiles 15,16

    // ---- block reduction -> one partial per block ----
#pragma unroll
    for (int off = 32; off > 0; off >>= 1)
        lsum += __shfl_down(lsum, off);
    if (lane == 0) wsum[wv] = lsum;
    __syncthreads();
    if (tid == 0)
        partials[(plane * 2 + yh) * 8 + bx] =
            wsum[0] + wsum[1] + wsum[2] + wsum[3];
}

__global__ __launch_bounds__(1024) void ssim_finalize(
        const float* __restrict__ partials, float* __restrict__ out,
        int nparts, double inv_n)
{
    __shared__ double ws[16];
    double s = 0.0;
    for (int i = threadIdx.x; i < nparts; i += 1024)
        s += (double)partials[i];
#pragma unroll
    for (int off = 32; off > 0; off >>= 1)
        s += __shfl_down(s, off);
    if ((threadIdx.x & 63) == 0) ws[threadIdx.x >> 6] = s;
    __syncthreads();
    if (threadIdx.x == 0) {
        double t = 0.0;
#pragma unroll
        for (int i = 0; i < 16; ++i) t += ws[i];
        out[0] = (float)(1.0 - t * inv_n);
    }
}

extern "C" void kernel_launch(void* const* d_in, const int* in_sizes, int n_in,
                              void* d_out, int out_size, void* d_ws, size_t ws_size,
                              hipStream_t stream)
{
    const float* pred = (const float*)d_in[0];
    const float* gt   = (const float*)d_in[1];
    float* out        = (float*)d_out;
    float* partials   = (float*)d_ws;          // 8*2*48 = 768 floats

    const long n = (long)in_sizes[0];
    const int planes = (int)(n / (long)(IMG * IMG));   // B*C = 48

    dim3 grid(8, 2, planes);                   // 64-col x 256-row strips
    ssim_mfma_small<<<grid, 256, 0, stream>>>(pred, gt, partials);
    ssim_finalize<<<1, 1024, 0, stream>>>(partials, out,
                                          8 * 2 * planes, 1.0 / (double)n);
}